// Round 1
// baseline (759.588 us; speedup 1.0000x reference)
//
#include <hip/hip_runtime.h>
#include <hip/hip_bf16.h>

// GAT: 2-layer, N=50000 nodes, F=64 in-feats, H=4 heads, C=64, D=256, E=800000 edges (+N self loops)
// Output: softmax(mean_pool(layer2) @ cls_W + cls_b) -> [1,16] f32

#define NEG_SLOPE 0.2f

// ---------------- CSR build ----------------

__global__ void k_init_deg(int* deg, int N) {
    int i = blockIdx.x * blockDim.x + threadIdx.x;
    if (i < N) deg[i] = 1;  // self loop
}

__global__ void k_hist(const int* __restrict__ ei, int* __restrict__ deg, int E) {
    int i = blockIdx.x * blockDim.x + threadIdx.x;
    if (i < E) atomicAdd(&deg[ei[E + i]], 1);
}

// per-chunk exclusive scan; chunk = 256
__global__ void k_scan1(const int* __restrict__ deg, int* __restrict__ offs, int* __restrict__ sums, int N) {
    __shared__ int tmp[256];
    int t = threadIdx.x;
    int i = blockIdx.x * 256 + t;
    int v = (i < N) ? deg[i] : 0;
    tmp[t] = v;
    __syncthreads();
    for (int off = 1; off < 256; off <<= 1) {
        int add = (t >= off) ? tmp[t - off] : 0;
        __syncthreads();
        tmp[t] += add;
        __syncthreads();
    }
    if (i < N) offs[i] = tmp[t] - v;
    if (t == 255) sums[blockIdx.x] = tmp[255];
}

// scan chunk sums (requires nb <= 256; N=50000 -> nb=196)
__global__ void k_scan2(int* __restrict__ sums, int* __restrict__ offs, int nb, int N) {
    __shared__ int tmp[256];
    int t = threadIdx.x;
    int v = (t < nb) ? sums[t] : 0;
    tmp[t] = v;
    __syncthreads();
    for (int off = 1; off < 256; off <<= 1) {
        int add = (t >= off) ? tmp[t - off] : 0;
        __syncthreads();
        tmp[t] += add;
        __syncthreads();
    }
    if (t < nb) sums[t] = tmp[t] - v;
    if (t == 255) offs[N] = tmp[255];  // grand total = E + N
}

__global__ void k_scan3(int* __restrict__ offs, int* __restrict__ cursor, const int* __restrict__ sums, int N) {
    int i = blockIdx.x * 256 + threadIdx.x;
    if (i < N) {
        int o = offs[i] + sums[blockIdx.x];
        offs[i] = o;
        cursor[i] = o;
    }
}

__global__ void k_fill(const int* __restrict__ ei, int* __restrict__ cursor, int* __restrict__ adj, int N, int E) {
    int i = blockIdx.x * blockDim.x + threadIdx.x;
    if (i >= E + N) return;
    int s, d;
    if (i < E) { s = ei[i]; d = ei[E + i]; }
    else       { s = i - E; d = i - E; }
    int pos = atomicAdd(&cursor[d], 1);
    adj[pos] = s;
}

// ---------------- GEMM: Out[N][256] = In[N][K] @ W[K][256] ----------------
// block 256, tile 32 rows x 256 cols, micro-tile 4x8 per thread

template<int K>
__global__ __launch_bounds__(256, 2) void k_gemm(const float* __restrict__ In,
                                                 const float* __restrict__ W,
                                                 float* __restrict__ Out, int N) {
    __shared__ float Ws[64 * 256];   // [kk][c]
    __shared__ float Ins[64 * 36];   // [kk][r], pad 36 (144B rows, 16B aligned)
    const int t = threadIdx.x;
    const int row0 = blockIdx.x * 32;
    const int tc = t & 31;   // cols tc*8 .. tc*8+7
    const int tr = t >> 5;   // rows tr*4 .. tr*4+3
    float acc[4][8];
#pragma unroll
    for (int i = 0; i < 4; ++i)
#pragma unroll
        for (int j = 0; j < 8; ++j) acc[i][j] = 0.f;

    for (int k0 = 0; k0 < K; k0 += 64) {
        {   // stage W chunk: 64x256 floats
            const int c4 = (t & 63) * 4;
            const int kb = t >> 6;  // 0..3
#pragma unroll
            for (int p = 0; p < 16; ++p) {
                int kk = p * 4 + kb;
                float4 w = *(const float4*)&W[(size_t)(k0 + kk) * 256 + c4];
                *(float4*)&Ws[kk * 256 + c4] = w;
            }
        }
        {   // stage In chunk transposed -> Ins[kk][r]
#pragma unroll
            for (int p = 0; p < 2; ++p) {
                int r = p * 16 + (t >> 4);
                int k4 = (t & 15) * 4;
                int row = row0 + r;
                float4 v = make_float4(0.f, 0.f, 0.f, 0.f);
                if (row < N) v = *(const float4*)&In[(size_t)row * K + k0 + k4];
                Ins[(k4 + 0) * 36 + r] = v.x;
                Ins[(k4 + 1) * 36 + r] = v.y;
                Ins[(k4 + 2) * 36 + r] = v.z;
                Ins[(k4 + 3) * 36 + r] = v.w;
            }
        }
        __syncthreads();
#pragma unroll 8
        for (int kk = 0; kk < 64; ++kk) {
            float4 a  = *(const float4*)&Ins[kk * 36 + tr * 4];
            float4 bA = *(const float4*)&Ws[kk * 256 + tc * 8];
            float4 bB = *(const float4*)&Ws[kk * 256 + tc * 8 + 4];
            float av[4] = {a.x, a.y, a.z, a.w};
            float bv[8] = {bA.x, bA.y, bA.z, bA.w, bB.x, bB.y, bB.z, bB.w};
#pragma unroll
            for (int i = 0; i < 4; ++i)
#pragma unroll
                for (int j = 0; j < 8; ++j)
                    acc[i][j] = fmaf(av[i], bv[j], acc[i][j]);
        }
        __syncthreads();
    }
#pragma unroll
    for (int i = 0; i < 4; ++i) {
        int row = row0 + tr * 4 + i;
        if (row < N) {
            float4 o0 = {acc[i][0], acc[i][1], acc[i][2], acc[i][3]};
            float4 o1 = {acc[i][4], acc[i][5], acc[i][6], acc[i][7]};
            *(float4*)&Out[(size_t)row * 256 + tc * 8]     = o0;
            *(float4*)&Out[(size_t)row * 256 + tc * 8 + 4] = o1;
        }
    }
}

// ---------------- attention dots: al[n][h] = sum_c P[n][h][c] * a[h][c] ----------------

__global__ __launch_bounds__(256) void k_attdot(const float* __restrict__ P,
                                                const float* __restrict__ asrc,
                                                const float* __restrict__ adst,
                                                float* __restrict__ alsrc,
                                                float* __restrict__ aldst, int N) {
    int n = blockIdx.x;
    int t = threadIdx.x;
    float v = P[(size_t)n * 256 + t];
    float ps = v * asrc[t];
    float pd = v * adst[t];
#pragma unroll
    for (int off = 32; off; off >>= 1) {
        ps += __shfl_xor(ps, off, 64);
        pd += __shfl_xor(pd, off, 64);
    }
    if ((t & 63) == 0) {
        int h = t >> 6;
        alsrc[(size_t)n * 4 + h] = ps;
        aldst[(size_t)n * 4 + h] = pd;
    }
}

// ---------------- aggregation: segment softmax + weighted gather-sum ----------------
// one block (256 thr) per destination node; channel = tid, head = tid/64

__device__ __forceinline__ float leaky(float e) { return fmaxf(e, NEG_SLOPE * e); }

__global__ __launch_bounds__(256) void k_agg(const float* __restrict__ P,
                                             const float* __restrict__ alsrc,
                                             const float* __restrict__ aldst,
                                             const int* __restrict__ offs,
                                             const int* __restrict__ adj,
                                             const float* __restrict__ bias,
                                             float* __restrict__ out, int N, int do_elu) {
    const int d = blockIdx.x;
    const int t = threadIdx.x;
    const int head = t >> 6;
    const int lane = t & 63;
    __shared__ float s_w[256 * 4];
    __shared__ int   s_adj[256];
    __shared__ float s_m[4], s_rden[4];
    __shared__ float s_red[4][8];

    const int s0 = offs[d];
    const int deg = offs[d + 1] - s0;
    const float4 ad = *(const float4*)&aldst[(size_t)d * 4];

    // phase A: online (max, sum-exp) per head, strided over edges
    float m0 = -1e30f, m1 = -1e30f, m2 = -1e30f, m3 = -1e30f;
    float d0 = 0.f, d1 = 0.f, d2 = 0.f, d3 = 0.f;
    for (int j = t; j < deg; j += 256) {
        int s = adj[s0 + j];
        float4 as = *(const float4*)&alsrc[(size_t)s * 4];
        float e0 = leaky(as.x + ad.x);
        float e1 = leaky(as.y + ad.y);
        float e2 = leaky(as.z + ad.z);
        float e3 = leaky(as.w + ad.w);
        if (e0 > m0) { d0 *= __expf(m0 - e0); m0 = e0; } d0 += __expf(e0 - m0);
        if (e1 > m1) { d1 *= __expf(m1 - e1); m1 = e1; } d1 += __expf(e1 - m1);
        if (e2 > m2) { d2 *= __expf(m2 - e2); m2 = e2; } d2 += __expf(e2 - m2);
        if (e3 > m3) { d3 *= __expf(m3 - e3); m3 = e3; } d3 += __expf(e3 - m3);
    }
    // wave-level merge
#pragma unroll
    for (int off = 1; off < 64; off <<= 1) {
        float om, od, M;
        om = __shfl_xor(m0, off, 64); od = __shfl_xor(d0, off, 64);
        M = fmaxf(m0, om); d0 = d0 * __expf(m0 - M) + od * __expf(om - M); m0 = M;
        om = __shfl_xor(m1, off, 64); od = __shfl_xor(d1, off, 64);
        M = fmaxf(m1, om); d1 = d1 * __expf(m1 - M) + od * __expf(om - M); m1 = M;
        om = __shfl_xor(m2, off, 64); od = __shfl_xor(d2, off, 64);
        M = fmaxf(m2, om); d2 = d2 * __expf(m2 - M) + od * __expf(om - M); m2 = M;
        om = __shfl_xor(m3, off, 64); od = __shfl_xor(d3, off, 64);
        M = fmaxf(m3, om); d3 = d3 * __expf(m3 - M) + od * __expf(om - M); m3 = M;
    }
    if (lane == 0) {
        int w = t >> 6;
        s_red[w][0] = m0; s_red[w][1] = d0;
        s_red[w][2] = m1; s_red[w][3] = d1;
        s_red[w][4] = m2; s_red[w][5] = d2;
        s_red[w][6] = m3; s_red[w][7] = d3;
    }
    __syncthreads();
    if (t < 4) {
        float M = s_red[0][t * 2], D = s_red[0][t * 2 + 1];
#pragma unroll
        for (int w = 1; w < 4; ++w) {
            float om = s_red[w][t * 2], od = s_red[w][t * 2 + 1];
            float M2 = fmaxf(M, om);
            D = D * __expf(M - M2) + od * __expf(om - M2);
            M = M2;
        }
        s_m[t] = M;
        s_rden[t] = 1.0f / D;
    }
    __syncthreads();

    // phase B: weighted accumulation, channel-per-thread
    float acc = 0.f;
    for (int base = 0; base < deg; base += 256) {
        int cl = min(256, deg - base);
        if (t < cl) {
            int s = adj[s0 + base + t];
            s_adj[t] = s;
            float4 as = *(const float4*)&alsrc[(size_t)s * 4];
            s_w[t * 4 + 0] = __expf(leaky(as.x + ad.x) - s_m[0]) * s_rden[0];
            s_w[t * 4 + 1] = __expf(leaky(as.y + ad.y) - s_m[1]) * s_rden[1];
            s_w[t * 4 + 2] = __expf(leaky(as.z + ad.z) - s_m[2]) * s_rden[2];
            s_w[t * 4 + 3] = __expf(leaky(as.w + ad.w) - s_m[3]) * s_rden[3];
        }
        __syncthreads();
        for (int j = 0; j < cl; ++j) {
            acc = fmaf(s_w[j * 4 + head], P[(size_t)s_adj[j] * 256 + t], acc);
        }
        __syncthreads();
    }
    float val = acc + bias[t];
    if (do_elu) val = (val > 0.f) ? val : (__expf(val) - 1.f);
    out[(size_t)d * 256 + t] = val;
    (void)lane;
}

// ---------------- mean pool (column sums) ----------------

__global__ __launch_bounds__(256) void k_pool(const float* __restrict__ A, float* __restrict__ pooled, int N) {
    int t = threadIdx.x;
    float acc = 0.f;
    for (int r = blockIdx.x; r < N; r += gridDim.x)
        acc += A[(size_t)r * 256 + t];
    atomicAdd(&pooled[t], acc);
}

// ---------------- classifier + softmax ----------------

__global__ void k_final(const float* __restrict__ pooled, const float* __restrict__ clsW,
                        const float* __restrict__ clsb, float* __restrict__ out, int N) {
    int t = threadIdx.x;  // 64 threads
    float logit = -1e30f;
    if (t < 16) {
        float acc = 0.f;
        for (int k = 0; k < 256; ++k)
            acc = fmaf(pooled[k], clsW[k * 16 + t], acc);
        logit = acc / (float)N + clsb[t];
    }
    float mx = logit;
#pragma unroll
    for (int off = 1; off < 16; off <<= 1) mx = fmaxf(mx, __shfl_xor(mx, off, 64));
    float ex = __expf(logit - mx);
    float sm = ex;
#pragma unroll
    for (int off = 1; off < 16; off <<= 1) sm += __shfl_xor(sm, off, 64);
    if (t < 16) out[t] = ex / sm;
}

// ---------------- launch ----------------

extern "C" void kernel_launch(void* const* d_in, const int* in_sizes, int n_in,
                              void* d_out, int out_size, void* d_ws, size_t ws_size,
                              hipStream_t stream) {
    const float* x     = (const float*)d_in[0];
    const int*   ei    = (const int*)d_in[1];
    const float* W0    = (const float*)d_in[2];
    const float* a0src = (const float*)d_in[3];
    const float* a0dst = (const float*)d_in[4];
    const float* b0    = (const float*)d_in[5];
    const float* W1    = (const float*)d_in[6];
    const float* a1src = (const float*)d_in[7];
    const float* a1dst = (const float*)d_in[8];
    const float* b1    = (const float*)d_in[9];
    const float* clsW  = (const float*)d_in[10];
    const float* clsb  = (const float*)d_in[11];
    float* out = (float*)d_out;

    const int N = in_sizes[0] / 64;   // 50000
    const int E = in_sizes[1] / 2;    // 800000

    char* w = (char*)d_ws;
    auto alloc = [&](size_t bytes) {
        char* p = w;
        w += (bytes + 255) & ~(size_t)255;
        return p;
    };
    float* P      = (float*)alloc((size_t)N * 256 * 4);
    float* A      = (float*)alloc((size_t)N * 256 * 4);
    float* alsrc  = (float*)alloc((size_t)N * 4 * 4);
    float* aldst  = (float*)alloc((size_t)N * 4 * 4);
    int*   deg    = (int*)alloc((size_t)N * 4);
    int*   offs   = (int*)alloc((size_t)(N + 1) * 4);
    int*   cursor = (int*)alloc((size_t)N * 4);
    int*   sums   = (int*)alloc(1024 * 4);
    int*   adj    = (int*)alloc((size_t)(E + N) * 4);
    float* pooled = (float*)alloc(256 * 4);

    const int NB = (N + 255) / 256;  // 196 (must be <= 256 for k_scan2)

    hipMemsetAsync(pooled, 0, 256 * 4, stream);

    // CSR build (by destination), includes self loops
    k_init_deg<<<NB, 256, 0, stream>>>(deg, N);
    k_hist<<<(E + 255) / 256, 256, 0, stream>>>(ei, deg, E);
    k_scan1<<<NB, 256, 0, stream>>>(deg, offs, sums, N);
    k_scan2<<<1, 256, 0, stream>>>(sums, offs, NB, N);
    k_scan3<<<NB, 256, 0, stream>>>(offs, cursor, sums, N);
    k_fill<<<(E + N + 255) / 256, 256, 0, stream>>>(ei, cursor, adj, N, E);

    // ---- layer 0 ----
    k_gemm<64><<<(N + 31) / 32, 256, 0, stream>>>(x, W0, P, N);
    k_attdot<<<N, 256, 0, stream>>>(P, a0src, a0dst, alsrc, aldst, N);
    k_agg<<<N, 256, 0, stream>>>(P, alsrc, aldst, offs, adj, b0, A, N, /*do_elu=*/1);

    // ---- layer 1 ----
    k_gemm<256><<<(N + 31) / 32, 256, 0, stream>>>(A, W1, P, N);
    k_attdot<<<N, 256, 0, stream>>>(P, a1src, a1dst, alsrc, aldst, N);
    k_agg<<<N, 256, 0, stream>>>(P, alsrc, aldst, offs, adj, b1, A, N, /*do_elu=*/0);

    // ---- pool + classify + softmax ----
    k_pool<<<256, 256, 0, stream>>>(A, pooled, N);
    k_final<<<1, 64, 0, stream>>>(pooled, clsW, clsb, out, N);
}

// Round 2
// 648.649 us; speedup vs baseline: 1.1710x; 1.1710x over previous
//
#include <hip/hip_runtime.h>
#include <hip/hip_bf16.h>

// GAT: 2-layer, N=50000, F=64, H=4, C=64, D=256, E=800000 (+N self loops)
// out = softmax(mean_pool(layer2) @ cls_W + cls_b) -> [1,16] f32

#define NEG_SLOPE 0.2f
__device__ __forceinline__ float leaky(float e) { return fmaxf(e, NEG_SLOPE * e); }

// ---------------- CSR build ----------------

__global__ void k_init(int* deg, float* pooled, int N) {
    int i = blockIdx.x * blockDim.x + threadIdx.x;
    if (i < N) deg[i] = 1;  // self loop
    if (blockIdx.x == 0 && threadIdx.x < 256) pooled[threadIdx.x] = 0.f;
}

__global__ void k_hist(const int* __restrict__ ei, int* __restrict__ deg, int E) {
    int i = blockIdx.x * blockDim.x + threadIdx.x;
    if (i < E) atomicAdd(&deg[ei[E + i]], 1);
}

__global__ void k_scan1(const int* __restrict__ deg, int* __restrict__ offs, int* __restrict__ sums, int N) {
    __shared__ int tmp[256];
    int t = threadIdx.x;
    int i = blockIdx.x * 256 + t;
    int v = (i < N) ? deg[i] : 0;
    tmp[t] = v;
    __syncthreads();
    for (int off = 1; off < 256; off <<= 1) {
        int add = (t >= off) ? tmp[t - off] : 0;
        __syncthreads();
        tmp[t] += add;
        __syncthreads();
    }
    if (i < N) offs[i] = tmp[t] - v;
    if (t == 255) sums[blockIdx.x] = tmp[255];
}

__global__ void k_scan2(int* __restrict__ sums, int* __restrict__ offs, int nb, int N) {
    __shared__ int tmp[256];
    int t = threadIdx.x;
    int v = (t < nb) ? sums[t] : 0;
    tmp[t] = v;
    __syncthreads();
    for (int off = 1; off < 256; off <<= 1) {
        int add = (t >= off) ? tmp[t - off] : 0;
        __syncthreads();
        tmp[t] += add;
        __syncthreads();
    }
    if (t < nb) sums[t] = tmp[t] - v;
    if (t == 255) offs[N] = tmp[255];
}

__global__ void k_scan3(int* __restrict__ offs, int* __restrict__ cursor, const int* __restrict__ sums, int N) {
    int i = blockIdx.x * 256 + threadIdx.x;
    if (i < N) {
        int o = offs[i] + sums[blockIdx.x];
        offs[i] = o;
        cursor[i] = o;
    }
}

__global__ void k_fill(const int* __restrict__ ei, int* __restrict__ cursor, int* __restrict__ adj, int N, int E) {
    int i = blockIdx.x * blockDim.x + threadIdx.x;
    if (i >= E + N) return;
    int s, d;
    if (i < E) { s = ei[i]; d = ei[E + i]; }
    else       { s = i - E; d = i - E; }
    int pos = atomicAdd(&cursor[d], 1);
    adj[pos] = s;
}

// ---------------- GEMM + fused attention dots ----------------
// Out[N][256] = In[N][K] @ W[K][256]; alsrc/aldst[n][h] = sum_c Out[n][h*64+c]*a[h][c]
// block 256, tile 32 rows x 256 cols, micro-tile 4x8 per thread

template<int K>
__global__ __launch_bounds__(256, 2) void k_gemm(const float* __restrict__ In,
                                                 const float* __restrict__ W,
                                                 const float* __restrict__ asrc,
                                                 const float* __restrict__ adst,
                                                 float* __restrict__ Out,
                                                 float* __restrict__ alsrc,
                                                 float* __restrict__ aldst, int N) {
    __shared__ float Ws[64 * 256];   // [kk][c]
    __shared__ float Ins[64 * 36];   // [kk][r] padded
    const int t = threadIdx.x;
    const int row0 = blockIdx.x * 32;
    const int tc = t & 31;
    const int tr = t >> 5;
    float acc[4][8];
#pragma unroll
    for (int i = 0; i < 4; ++i)
#pragma unroll
        for (int j = 0; j < 8; ++j) acc[i][j] = 0.f;

    for (int k0 = 0; k0 < K; k0 += 64) {
        {
            const int c4 = (t & 63) * 4;
            const int kb = t >> 6;
#pragma unroll
            for (int p = 0; p < 16; ++p) {
                int kk = p * 4 + kb;
                float4 w = *(const float4*)&W[(size_t)(k0 + kk) * 256 + c4];
                *(float4*)&Ws[kk * 256 + c4] = w;
            }
        }
        {
#pragma unroll
            for (int p = 0; p < 2; ++p) {
                int r = p * 16 + (t >> 4);
                int k4 = (t & 15) * 4;
                int row = row0 + r;
                float4 v = make_float4(0.f, 0.f, 0.f, 0.f);
                if (row < N) v = *(const float4*)&In[(size_t)row * K + k0 + k4];
                Ins[(k4 + 0) * 36 + r] = v.x;
                Ins[(k4 + 1) * 36 + r] = v.y;
                Ins[(k4 + 2) * 36 + r] = v.z;
                Ins[(k4 + 3) * 36 + r] = v.w;
            }
        }
        __syncthreads();
#pragma unroll 8
        for (int kk = 0; kk < 64; ++kk) {
            float4 a  = *(const float4*)&Ins[kk * 36 + tr * 4];
            float4 bA = *(const float4*)&Ws[kk * 256 + tc * 8];
            float4 bB = *(const float4*)&Ws[kk * 256 + tc * 8 + 4];
            float av[4] = {a.x, a.y, a.z, a.w};
            float bv[8] = {bA.x, bA.y, bA.z, bA.w, bB.x, bB.y, bB.z, bB.w};
#pragma unroll
            for (int i = 0; i < 4; ++i)
#pragma unroll
                for (int j = 0; j < 8; ++j)
                    acc[i][j] = fmaf(av[i], bv[j], acc[i][j]);
        }
        __syncthreads();
    }
    // store tile
#pragma unroll
    for (int i = 0; i < 4; ++i) {
        int row = row0 + tr * 4 + i;
        if (row < N) {
            float4 o0 = {acc[i][0], acc[i][1], acc[i][2], acc[i][3]};
            float4 o1 = {acc[i][4], acc[i][5], acc[i][6], acc[i][7]};
            *(float4*)&Out[(size_t)row * 256 + tc * 8]     = o0;
            *(float4*)&Out[(size_t)row * 256 + tc * 8 + 4] = o1;
        }
    }
    // fused attention dots: this thread's 8 cols are all in head tc>>3
    float psrc[4] = {0.f, 0.f, 0.f, 0.f};
    float pdst[4] = {0.f, 0.f, 0.f, 0.f};
#pragma unroll
    for (int j = 0; j < 8; ++j) {
        int col = tc * 8 + j;
        float as = asrc[col];
        float av = adst[col];
#pragma unroll
        for (int i = 0; i < 4; ++i) {
            psrc[i] = fmaf(acc[i][j], as, psrc[i]);
            pdst[i] = fmaf(acc[i][j], av, pdst[i]);
        }
    }
#pragma unroll
    for (int off = 1; off < 8; off <<= 1) {
#pragma unroll
        for (int i = 0; i < 4; ++i) {
            psrc[i] += __shfl_xor(psrc[i], off, 64);
            pdst[i] += __shfl_xor(pdst[i], off, 64);
        }
    }
    if ((tc & 7) == 0) {
        int h = tc >> 3;
#pragma unroll
        for (int i = 0; i < 4; ++i) {
            int row = row0 + tr * 4 + i;
            if (row < N) {
                alsrc[(size_t)row * 4 + h] = psrc[i];
                aldst[(size_t)row * 4 + h] = pdst[i];
            }
        }
    }
}

// ---------------- aggregation: one WAVE per dst node, float4 channels ----------------
// lane owns channels lane*4..lane*4+3 (head = lane>>4); per edge: one dwordx4 gather + 4 fmaf

__global__ __launch_bounds__(256) void k_agg(const float* __restrict__ P,
                                             const float* __restrict__ alsrc,
                                             const float* __restrict__ aldst,
                                             const int* __restrict__ offs,
                                             const int* __restrict__ adj,
                                             const float* __restrict__ bias,
                                             float* __restrict__ out, int N, int do_elu) {
    const int wv = threadIdx.x >> 6;
    const int lane = threadIdx.x & 63;
    const int d = blockIdx.x * 4 + wv;
    __shared__ float s_w[4][256];
    __shared__ int s_off[4][64];
    if (d >= N) return;

    const int s0 = offs[d];
    const int deg = offs[d + 1] - s0;
    const float4 ad = *(const float4*)&aldst[(size_t)d * 4];

    // first chunk: edge `lane` kept in registers
    int sfirst = 0;
    float4 e0 = make_float4(-1e30f, -1e30f, -1e30f, -1e30f);
    if (lane < deg) {
        sfirst = adj[s0 + lane];
        float4 as = *(const float4*)&alsrc[(size_t)sfirst * 4];
        e0.x = leaky(as.x + ad.x);
        e0.y = leaky(as.y + ad.y);
        e0.z = leaky(as.z + ad.z);
        e0.w = leaky(as.w + ad.w);
    }
    float4 mx = e0;
    for (int j = lane + 64; j < deg; j += 64) {
        int s = adj[s0 + j];
        float4 as = *(const float4*)&alsrc[(size_t)s * 4];
        mx.x = fmaxf(mx.x, leaky(as.x + ad.x));
        mx.y = fmaxf(mx.y, leaky(as.y + ad.y));
        mx.z = fmaxf(mx.z, leaky(as.z + ad.z));
        mx.w = fmaxf(mx.w, leaky(as.w + ad.w));
    }
#pragma unroll
    for (int off = 1; off < 64; off <<= 1) {
        mx.x = fmaxf(mx.x, __shfl_xor(mx.x, off, 64));
        mx.y = fmaxf(mx.y, __shfl_xor(mx.y, off, 64));
        mx.z = fmaxf(mx.z, __shfl_xor(mx.z, off, 64));
        mx.w = fmaxf(mx.w, __shfl_xor(mx.w, off, 64));
    }
    // sum of exp
    float4 sm = make_float4(0.f, 0.f, 0.f, 0.f);
    if (lane < deg) {
        sm.x = __expf(e0.x - mx.x);
        sm.y = __expf(e0.y - mx.y);
        sm.z = __expf(e0.z - mx.z);
        sm.w = __expf(e0.w - mx.w);
    }
    for (int j = lane + 64; j < deg; j += 64) {
        int s = adj[s0 + j];
        float4 as = *(const float4*)&alsrc[(size_t)s * 4];
        sm.x += __expf(leaky(as.x + ad.x) - mx.x);
        sm.y += __expf(leaky(as.y + ad.y) - mx.y);
        sm.z += __expf(leaky(as.z + ad.z) - mx.z);
        sm.w += __expf(leaky(as.w + ad.w) - mx.w);
    }
#pragma unroll
    for (int off = 1; off < 64; off <<= 1) {
        sm.x += __shfl_xor(sm.x, off, 64);
        sm.y += __shfl_xor(sm.y, off, 64);
        sm.z += __shfl_xor(sm.z, off, 64);
        sm.w += __shfl_xor(sm.w, off, 64);
    }
    float4 rd = make_float4(1.f / sm.x, 1.f / sm.y, 1.f / sm.z, 1.f / sm.w);

    // accumulate: per edge one dwordx4 per lane (wave reads full 1KB row)
    const int head = lane >> 4;
    float4 acc = make_float4(0.f, 0.f, 0.f, 0.f);
    const char* Pb = (const char*)P + (size_t)lane * 16;

    for (int base = 0; base < deg; base += 64) {
        int cl = min(64, deg - base);
        if (lane < cl) {
            float4 w;
            int s;
            if (base == 0) {
                s = sfirst;
                w.x = __expf(e0.x - mx.x) * rd.x;
                w.y = __expf(e0.y - mx.y) * rd.y;
                w.z = __expf(e0.z - mx.z) * rd.z;
                w.w = __expf(e0.w - mx.w) * rd.w;
            } else {
                s = adj[s0 + base + lane];
                float4 as = *(const float4*)&alsrc[(size_t)s * 4];
                w.x = __expf(leaky(as.x + ad.x) - mx.x) * rd.x;
                w.y = __expf(leaky(as.y + ad.y) - mx.y) * rd.y;
                w.z = __expf(leaky(as.z + ad.z) - mx.z) * rd.z;
                w.w = __expf(leaky(as.w + ad.w) - mx.w) * rd.w;
            }
            *(float4*)&s_w[wv][lane * 4] = w;
            s_off[wv][lane] = s << 10;  // byte offset of row (256 floats)
        }
        // per-wave LDS, in-order within wave: no block barrier needed (deg varies per wave)
#pragma unroll 2
        for (int j = 0; j < cl; ++j) {
            float wgt = s_w[wv][j * 4 + head];
            int off = s_off[wv][j];
            float4 p = *(const float4*)(Pb + off);
            acc.x = fmaf(wgt, p.x, acc.x);
            acc.y = fmaf(wgt, p.y, acc.y);
            acc.z = fmaf(wgt, p.z, acc.z);
            acc.w = fmaf(wgt, p.w, acc.w);
        }
    }

    float4 b4 = *(const float4*)&bias[lane * 4];
    float4 v = make_float4(acc.x + b4.x, acc.y + b4.y, acc.z + b4.z, acc.w + b4.w);
    if (do_elu) {
        v.x = (v.x > 0.f) ? v.x : (__expf(v.x) - 1.f);
        v.y = (v.y > 0.f) ? v.y : (__expf(v.y) - 1.f);
        v.z = (v.z > 0.f) ? v.z : (__expf(v.z) - 1.f);
        v.w = (v.w > 0.f) ? v.w : (__expf(v.w) - 1.f);
    }
    *(float4*)&out[(size_t)d * 256 + lane * 4] = v;
}

// ---------------- mean pool (column sums) ----------------

__global__ __launch_bounds__(256) void k_pool(const float* __restrict__ A, float* __restrict__ pooled, int N) {
    int t = threadIdx.x;
    float acc = 0.f;
    for (int r = blockIdx.x; r < N; r += gridDim.x)
        acc += A[(size_t)r * 256 + t];
    atomicAdd(&pooled[t], acc);
}

// ---------------- classifier + softmax ----------------

__global__ void k_final(const float* __restrict__ pooled, const float* __restrict__ clsW,
                        const float* __restrict__ clsb, float* __restrict__ out, int N) {
    int t = threadIdx.x;  // 64 threads
    float logit = -1e30f;
    if (t < 16) {
        float acc = 0.f;
        for (int k = 0; k < 256; ++k)
            acc = fmaf(pooled[k], clsW[k * 16 + t], acc);
        logit = acc / (float)N + clsb[t];
    }
    float mx = logit;
#pragma unroll
    for (int off = 1; off < 16; off <<= 1) mx = fmaxf(mx, __shfl_xor(mx, off, 64));
    float ex = __expf(logit - mx);
    float sm = ex;
#pragma unroll
    for (int off = 1; off < 16; off <<= 1) sm += __shfl_xor(sm, off, 64);
    if (t < 16) out[t] = ex / sm;
}

// ---------------- launch ----------------

extern "C" void kernel_launch(void* const* d_in, const int* in_sizes, int n_in,
                              void* d_out, int out_size, void* d_ws, size_t ws_size,
                              hipStream_t stream) {
    const float* x     = (const float*)d_in[0];
    const int*   ei    = (const int*)d_in[1];
    const float* W0    = (const float*)d_in[2];
    const float* a0src = (const float*)d_in[3];
    const float* a0dst = (const float*)d_in[4];
    const float* b0    = (const float*)d_in[5];
    const float* W1    = (const float*)d_in[6];
    const float* a1src = (const float*)d_in[7];
    const float* a1dst = (const float*)d_in[8];
    const float* b1    = (const float*)d_in[9];
    const float* clsW  = (const float*)d_in[10];
    const float* clsb  = (const float*)d_in[11];
    float* out = (float*)d_out;

    const int N = in_sizes[0] / 64;   // 50000
    const int E = in_sizes[1] / 2;    // 800000

    char* w = (char*)d_ws;
    auto alloc = [&](size_t bytes) {
        char* p = w;
        w += (bytes + 255) & ~(size_t)255;
        return p;
    };
    float* P      = (float*)alloc((size_t)N * 256 * 4);
    float* A      = (float*)alloc((size_t)N * 256 * 4);
    float* alsrc  = (float*)alloc((size_t)N * 4 * 4);
    float* aldst  = (float*)alloc((size_t)N * 4 * 4);
    int*   deg    = (int*)alloc((size_t)N * 4);
    int*   offs   = (int*)alloc((size_t)(N + 1) * 4);
    int*   cursor = (int*)alloc((size_t)N * 4);
    int*   sums   = (int*)alloc(1024 * 4);
    int*   adj    = (int*)alloc((size_t)(E + N) * 4);
    float* pooled = (float*)alloc(256 * 4);

    const int NB = (N + 255) / 256;  // 196 (<= 256 for k_scan2)

    // CSR build (by destination), includes self loops; also zeroes `pooled`
    k_init<<<NB, 256, 0, stream>>>(deg, pooled, N);
    k_hist<<<(E + 255) / 256, 256, 0, stream>>>(ei, deg, E);
    k_scan1<<<NB, 256, 0, stream>>>(deg, offs, sums, N);
    k_scan2<<<1, 256, 0, stream>>>(sums, offs, NB, N);
    k_scan3<<<NB, 256, 0, stream>>>(offs, cursor, sums, N);
    k_fill<<<(E + N + 255) / 256, 256, 0, stream>>>(ei, cursor, adj, N, E);

    // ---- layer 0 ----
    k_gemm<64><<<(N + 31) / 32, 256, 0, stream>>>(x, W0, a0src, a0dst, P, alsrc, aldst, N);
    k_agg<<<(N + 3) / 4, 256, 0, stream>>>(P, alsrc, aldst, offs, adj, b0, A, N, /*do_elu=*/1);

    // ---- layer 1 ----
    k_gemm<256><<<(N + 31) / 32, 256, 0, stream>>>(A, W1, a1src, a1dst, P, alsrc, aldst, N);
    k_agg<<<(N + 3) / 4, 256, 0, stream>>>(P, alsrc, aldst, offs, adj, b1, A, N, /*do_elu=*/0);

    // ---- pool + classify + softmax ----
    k_pool<<<256, 256, 0, stream>>>(A, pooled, N);
    k_final<<<1, 64, 0, stream>>>(pooled, clsW, clsb, out, N);
}

// Round 3
// 438.305 us; speedup vs baseline: 1.7330x; 1.4799x over previous
//
#include <hip/hip_runtime.h>
#include <hip/hip_bf16.h>

// GAT: 2-layer, N=50000, F=64, H=4, C=64, D=256, E=800000 (+N self loops)
// out = softmax(mean_pool(layer2) @ cls_W + cls_b) -> [1,16] f32
// bf16 datapath: MFMA GEMMs (f32 accum), bf16 feature gathers; attention logits f32.

#define NEG_SLOPE 0.2f
__device__ __forceinline__ float leaky(float e) { return fmaxf(e, NEG_SLOPE * e); }

typedef __bf16 bf16x8 __attribute__((ext_vector_type(8)));
typedef float  f32x4  __attribute__((ext_vector_type(4)));

__device__ __forceinline__ float bfbits2f(unsigned int hi_bits) {
    union { unsigned int i; float f; } c; c.i = hi_bits; return c.f;
}
__device__ __forceinline__ unsigned short f2bf(float f) {
    union { float f; unsigned int i; } c; c.f = f;
    unsigned int x = c.i;
    x += 0x7fffu + ((x >> 16) & 1u);   // RNE
    return (unsigned short)(x >> 16);
}

// ---------------- CSR build ----------------

__global__ void k_init(int* deg, float* pooled, int N) {
    int i = blockIdx.x * blockDim.x + threadIdx.x;
    if (i < N) deg[i] = 1;  // self loop
    if (blockIdx.x == 0 && threadIdx.x < 256) pooled[threadIdx.x] = 0.f;
}

__global__ void k_hist(const int* __restrict__ ei, int* __restrict__ deg, int E) {
    int i = blockIdx.x * blockDim.x + threadIdx.x;
    if (i < E) atomicAdd(&deg[ei[E + i]], 1);
}

__global__ void k_scan1(const int* __restrict__ deg, int* __restrict__ offs, int* __restrict__ sums, int N) {
    __shared__ int tmp[256];
    int t = threadIdx.x;
    int i = blockIdx.x * 256 + t;
    int v = (i < N) ? deg[i] : 0;
    tmp[t] = v;
    __syncthreads();
    for (int off = 1; off < 256; off <<= 1) {
        int add = (t >= off) ? tmp[t - off] : 0;
        __syncthreads();
        tmp[t] += add;
        __syncthreads();
    }
    if (i < N) offs[i] = tmp[t] - v;
    if (t == 255) sums[blockIdx.x] = tmp[255];
}

__global__ void k_scan2(int* __restrict__ sums, int* __restrict__ offs, int nb, int N) {
    __shared__ int tmp[256];
    int t = threadIdx.x;
    int v = (t < nb) ? sums[t] : 0;
    tmp[t] = v;
    __syncthreads();
    for (int off = 1; off < 256; off <<= 1) {
        int add = (t >= off) ? tmp[t - off] : 0;
        __syncthreads();
        tmp[t] += add;
        __syncthreads();
    }
    if (t < nb) sums[t] = tmp[t] - v;
    if (t == 255) offs[N] = tmp[255];
}

__global__ void k_scan3(int* __restrict__ offs, int* __restrict__ cursor, const int* __restrict__ sums, int N) {
    int i = blockIdx.x * 256 + threadIdx.x;
    if (i < N) {
        int o = offs[i] + sums[blockIdx.x];
        offs[i] = o;
        cursor[i] = o;
    }
}

__global__ void k_fill(const int* __restrict__ ei, int* __restrict__ cursor, int* __restrict__ adj, int N, int E) {
    int i = blockIdx.x * blockDim.x + threadIdx.x;
    if (i >= E + N) return;
    int s, d;
    if (i < E) { s = ei[i]; d = ei[E + i]; }
    else       { s = i - E; d = i - E; }
    int pos = atomicAdd(&cursor[d], 1);
    adj[pos] = s;
}

// ---------------- converts ----------------

__global__ void k_cvt(const float* __restrict__ in, unsigned short* __restrict__ out, int n4) {
    int i = (blockIdx.x * blockDim.x + threadIdx.x);
    if (i < n4) {
        float4 v = *(const float4*)&in[i * 4];
        ushort4 o;
        o.x = f2bf(v.x); o.y = f2bf(v.y); o.z = f2bf(v.z); o.w = f2bf(v.w);
        *(ushort4*)&out[i * 4] = o;
    }
}

// W[K][256] f32 -> WT[256][K] bf16
template<int K>
__global__ void k_cvt_wT(const float* __restrict__ W, unsigned short* __restrict__ WT) {
    int t = blockIdx.x * 256 + threadIdx.x;   // t < K*256
    int k = t & (K - 1);
    int c = t / K;
    WT[(size_t)c * K + k] = f2bf(W[(size_t)k * 256 + c]);
}

// ---------------- MFMA GEMM + fused attention dots ----------------
// P[N][256](bf16) = X[N][K](bf16) @ W[K][256]; al{src,dst}[n][h] = sum_c P*a (f32 accum)
// block 256 = 4 waves; tile 64 rows x 256 cols; wave w handles cols w*64.. (== head w)
// no LDS: A-frags from global rows, B-frags from pre-transposed WT (L2-resident)

template<int K>
__global__ __launch_bounds__(256) void k_gemm_mfma(const unsigned short* __restrict__ Xb,
                                                   const unsigned short* __restrict__ WT,
                                                   const float* __restrict__ asrc,
                                                   const float* __restrict__ adst,
                                                   unsigned short* __restrict__ P,
                                                   float* __restrict__ alsrc,
                                                   float* __restrict__ aldst, int N) {
    const int t = threadIdx.x;
    const int w = t >> 6;          // wave index = head = col block
    const int l = t & 63;
    const int l16 = l & 15;
    const int lg = l >> 4;         // k-group 0..3
    const int row0 = blockIdx.x * 64;
    const int colbase = w * 64;

    f32x4 acc[4][4];
#pragma unroll
    for (int i = 0; i < 4; ++i)
#pragma unroll
        for (int j = 0; j < 4; ++j) acc[i][j] = (f32x4){0.f, 0.f, 0.f, 0.f};

#pragma unroll
    for (int k0 = 0; k0 < K; k0 += 32) {
        bf16x8 a[4], b[4];
#pragma unroll
        for (int fi = 0; fi < 4; ++fi) {
            int r = row0 + fi * 16 + l16;
            r = (r < N) ? r : (N - 1);
            a[fi] = *(const bf16x8*)&Xb[(size_t)r * K + k0 + lg * 8];
        }
#pragma unroll
        for (int fj = 0; fj < 4; ++fj) {
            int c = colbase + fj * 16 + l16;
            b[fj] = *(const bf16x8*)&WT[(size_t)c * K + k0 + lg * 8];
        }
#pragma unroll
        for (int fi = 0; fi < 4; ++fi)
#pragma unroll
            for (int fj = 0; fj < 4; ++fj)
                acc[fi][fj] = __builtin_amdgcn_mfma_f32_16x16x32_bf16(a[fi], b[fj], acc[fi][fj], 0, 0, 0);
    }

    // epilogue: store bf16 P + fused attention dots (f32)
    float aSv[4], aDv[4];
#pragma unroll
    for (int fj = 0; fj < 4; ++fj) {
        aSv[fj] = asrc[colbase + fj * 16 + l16];
        aDv[fj] = adst[colbase + fj * 16 + l16];
    }
#pragma unroll
    for (int fi = 0; fi < 4; ++fi) {
#pragma unroll
        for (int r = 0; r < 4; ++r) {
            int row = row0 + fi * 16 + lg * 4 + r;
            bool ok = (row < N);
            float ps = 0.f, pd = 0.f;
#pragma unroll
            for (int fj = 0; fj < 4; ++fj) {
                float v = acc[fi][fj][r];
                if (ok) P[(size_t)row * 256 + colbase + fj * 16 + l16] = f2bf(v);
                ps = fmaf(v, aSv[fj], ps);
                pd = fmaf(v, aDv[fj], pd);
            }
#pragma unroll
            for (int off = 1; off < 16; off <<= 1) {
                ps += __shfl_xor(ps, off, 64);
                pd += __shfl_xor(pd, off, 64);
            }
            if (ok && l16 == 0) {
                alsrc[(size_t)row * 4 + w] = ps;
                aldst[(size_t)row * 4 + w] = pd;
            }
        }
    }
}

// ---------------- aggregation: one WAVE per dst node, bf16 gathers ----------------
// lane owns channels lane*4..lane*4+3 (head = lane>>4); per edge: one dwordx2 gather + 4 fmaf

__global__ __launch_bounds__(256) void k_agg(const unsigned short* __restrict__ P,
                                             const float* __restrict__ alsrc,
                                             const float* __restrict__ aldst,
                                             const int* __restrict__ offs,
                                             const int* __restrict__ adj,
                                             const float* __restrict__ bias,
                                             unsigned short* __restrict__ out, int N, int do_elu) {
    const int wv = threadIdx.x >> 6;
    const int lane = threadIdx.x & 63;
    const int d = blockIdx.x * 4 + wv;
    __shared__ float s_w[4][256];
    __shared__ int s_off[4][64];
    if (d >= N) return;

    const int s0 = offs[d];
    const int deg = offs[d + 1] - s0;
    const float4 ad = *(const float4*)&aldst[(size_t)d * 4];

    // first chunk of edges kept in registers
    int sfirst = 0;
    float4 e0 = make_float4(-1e30f, -1e30f, -1e30f, -1e30f);
    if (lane < deg) {
        sfirst = adj[s0 + lane];
        float4 as = *(const float4*)&alsrc[(size_t)sfirst * 4];
        e0.x = leaky(as.x + ad.x);
        e0.y = leaky(as.y + ad.y);
        e0.z = leaky(as.z + ad.z);
        e0.w = leaky(as.w + ad.w);
    }
    float4 mx = e0;
    for (int j = lane + 64; j < deg; j += 64) {
        int s = adj[s0 + j];
        float4 as = *(const float4*)&alsrc[(size_t)s * 4];
        mx.x = fmaxf(mx.x, leaky(as.x + ad.x));
        mx.y = fmaxf(mx.y, leaky(as.y + ad.y));
        mx.z = fmaxf(mx.z, leaky(as.z + ad.z));
        mx.w = fmaxf(mx.w, leaky(as.w + ad.w));
    }
#pragma unroll
    for (int off = 1; off < 64; off <<= 1) {
        mx.x = fmaxf(mx.x, __shfl_xor(mx.x, off, 64));
        mx.y = fmaxf(mx.y, __shfl_xor(mx.y, off, 64));
        mx.z = fmaxf(mx.z, __shfl_xor(mx.z, off, 64));
        mx.w = fmaxf(mx.w, __shfl_xor(mx.w, off, 64));
    }
    float4 sm = make_float4(0.f, 0.f, 0.f, 0.f);
    if (lane < deg) {
        sm.x = __expf(e0.x - mx.x);
        sm.y = __expf(e0.y - mx.y);
        sm.z = __expf(e0.z - mx.z);
        sm.w = __expf(e0.w - mx.w);
    }
    for (int j = lane + 64; j < deg; j += 64) {
        int s = adj[s0 + j];
        float4 as = *(const float4*)&alsrc[(size_t)s * 4];
        sm.x += __expf(leaky(as.x + ad.x) - mx.x);
        sm.y += __expf(leaky(as.y + ad.y) - mx.y);
        sm.z += __expf(leaky(as.z + ad.z) - mx.z);
        sm.w += __expf(leaky(as.w + ad.w) - mx.w);
    }
#pragma unroll
    for (int off = 1; off < 64; off <<= 1) {
        sm.x += __shfl_xor(sm.x, off, 64);
        sm.y += __shfl_xor(sm.y, off, 64);
        sm.z += __shfl_xor(sm.z, off, 64);
        sm.w += __shfl_xor(sm.w, off, 64);
    }
    float4 rd = make_float4(1.f / sm.x, 1.f / sm.y, 1.f / sm.z, 1.f / sm.w);

    // accumulate: per edge one dwordx2 (4 bf16) per lane; wave reads full 512B row
    const int head = lane >> 4;
    float4 acc = make_float4(0.f, 0.f, 0.f, 0.f);
    const char* Pb = (const char*)P + (size_t)lane * 8;

    for (int base = 0; base < deg; base += 64) {
        int cl = min(64, deg - base);
        if (lane < cl) {
            float4 wgt;
            int s;
            if (base == 0) {
                s = sfirst;
                wgt.x = __expf(e0.x - mx.x) * rd.x;
                wgt.y = __expf(e0.y - mx.y) * rd.y;
                wgt.z = __expf(e0.z - mx.z) * rd.z;
                wgt.w = __expf(e0.w - mx.w) * rd.w;
            } else {
                s = adj[s0 + base + lane];
                float4 as = *(const float4*)&alsrc[(size_t)s * 4];
                wgt.x = __expf(leaky(as.x + ad.x) - mx.x) * rd.x;
                wgt.y = __expf(leaky(as.y + ad.y) - mx.y) * rd.y;
                wgt.z = __expf(leaky(as.z + ad.z) - mx.z) * rd.z;
                wgt.w = __expf(leaky(as.w + ad.w) - mx.w) * rd.w;
            }
            *(float4*)&s_w[wv][lane * 4] = wgt;
            s_off[wv][lane] = s << 9;  // byte offset of bf16 row (256*2B)
        }
        // per-wave LDS, wave-internal ordering: no block barrier needed
#pragma unroll 2
        for (int j = 0; j < cl; ++j) {
            float wgt = s_w[wv][j * 4 + head];
            int off = s_off[wv][j];
            uint2 pv = *(const uint2*)(Pb + off);
            acc.x = fmaf(wgt, bfbits2f(pv.x << 16), acc.x);
            acc.y = fmaf(wgt, bfbits2f(pv.x & 0xffff0000u), acc.y);
            acc.z = fmaf(wgt, bfbits2f(pv.y << 16), acc.z);
            acc.w = fmaf(wgt, bfbits2f(pv.y & 0xffff0000u), acc.w);
        }
    }

    float4 b4 = *(const float4*)&bias[lane * 4];
    float4 v = make_float4(acc.x + b4.x, acc.y + b4.y, acc.z + b4.z, acc.w + b4.w);
    if (do_elu) {
        v.x = (v.x > 0.f) ? v.x : (__expf(v.x) - 1.f);
        v.y = (v.y > 0.f) ? v.y : (__expf(v.y) - 1.f);
        v.z = (v.z > 0.f) ? v.z : (__expf(v.z) - 1.f);
        v.w = (v.w > 0.f) ? v.w : (__expf(v.w) - 1.f);
    }
    ushort4 o;
    o.x = f2bf(v.x); o.y = f2bf(v.y); o.z = f2bf(v.z); o.w = f2bf(v.w);
    *(ushort4*)&out[(size_t)d * 256 + lane * 4] = o;
}

// ---------------- mean pool (column sums, bf16 input) ----------------

__global__ __launch_bounds__(256) void k_pool(const unsigned short* __restrict__ A, float* __restrict__ pooled, int N) {
    int t = threadIdx.x;
    float acc = 0.f;
    for (int r = blockIdx.x; r < N; r += gridDim.x)
        acc += bfbits2f(((unsigned int)A[(size_t)r * 256 + t]) << 16);
    atomicAdd(&pooled[t], acc);
}

// ---------------- classifier + softmax ----------------

__global__ void k_final(const float* __restrict__ pooled, const float* __restrict__ clsW,
                        const float* __restrict__ clsb, float* __restrict__ out, int N) {
    int t = threadIdx.x;  // 64 threads
    float logit = -1e30f;
    if (t < 16) {
        float acc = 0.f;
        for (int k = 0; k < 256; ++k)
            acc = fmaf(pooled[k], clsW[k * 16 + t], acc);
        logit = acc / (float)N + clsb[t];
    }
    float mx = logit;
#pragma unroll
    for (int off = 1; off < 16; off <<= 1) mx = fmaxf(mx, __shfl_xor(mx, off, 64));
    float ex = __expf(logit - mx);
    float sm = ex;
#pragma unroll
    for (int off = 1; off < 16; off <<= 1) sm += __shfl_xor(sm, off, 64);
    if (t < 16) out[t] = ex / sm;
}

// ---------------- launch ----------------

extern "C" void kernel_launch(void* const* d_in, const int* in_sizes, int n_in,
                              void* d_out, int out_size, void* d_ws, size_t ws_size,
                              hipStream_t stream) {
    const float* x     = (const float*)d_in[0];
    const int*   ei    = (const int*)d_in[1];
    const float* W0    = (const float*)d_in[2];
    const float* a0src = (const float*)d_in[3];
    const float* a0dst = (const float*)d_in[4];
    const float* b0    = (const float*)d_in[5];
    const float* W1    = (const float*)d_in[6];
    const float* a1src = (const float*)d_in[7];
    const float* a1dst = (const float*)d_in[8];
    const float* b1    = (const float*)d_in[9];
    const float* clsW  = (const float*)d_in[10];
    const float* clsb  = (const float*)d_in[11];
    float* out = (float*)d_out;

    const int N = in_sizes[0] / 64;   // 50000
    const int E = in_sizes[1] / 2;    // 800000

    char* w = (char*)d_ws;
    auto alloc = [&](size_t bytes) {
        char* p = w;
        w += (bytes + 255) & ~(size_t)255;
        return p;
    };
    unsigned short* Xb   = (unsigned short*)alloc((size_t)N * 64 * 2);
    unsigned short* W0T  = (unsigned short*)alloc((size_t)256 * 64 * 2);
    unsigned short* W1T  = (unsigned short*)alloc((size_t)256 * 256 * 2);
    unsigned short* P    = (unsigned short*)alloc((size_t)N * 256 * 2);
    unsigned short* A    = (unsigned short*)alloc((size_t)N * 256 * 2);
    float* alsrc  = (float*)alloc((size_t)N * 4 * 4);
    float* aldst  = (float*)alloc((size_t)N * 4 * 4);
    int*   deg    = (int*)alloc((size_t)N * 4);
    int*   offs   = (int*)alloc((size_t)(N + 1) * 4);
    int*   cursor = (int*)alloc((size_t)N * 4);
    int*   sums   = (int*)alloc(1024 * 4);
    int*   adj    = (int*)alloc((size_t)(E + N) * 4);
    float* pooled = (float*)alloc(256 * 4);

    const int NB = (N + 255) / 256;  // 196 (<= 256 for k_scan2)

    // CSR build (by destination), includes self loops; also zeroes `pooled`
    k_init<<<NB, 256, 0, stream>>>(deg, pooled, N);
    k_hist<<<(E + 255) / 256, 256, 0, stream>>>(ei, deg, E);
    k_scan1<<<NB, 256, 0, stream>>>(deg, offs, sums, N);
    k_scan2<<<1, 256, 0, stream>>>(sums, offs, NB, N);
    k_scan3<<<NB, 256, 0, stream>>>(offs, cursor, sums, N);
    k_fill<<<(E + N + 255) / 256, 256, 0, stream>>>(ei, cursor, adj, N, E);

    // converts
    k_cvt<<<(N * 64 / 4 + 255) / 256, 256, 0, stream>>>(x, Xb, N * 64 / 4);
    k_cvt_wT<64><<<64, 256, 0, stream>>>(W0, W0T);
    k_cvt_wT<256><<<256, 256, 0, stream>>>(W1, W1T);

    const int GB = (N + 63) / 64;  // 782

    // ---- layer 0 ----
    k_gemm_mfma<64><<<GB, 256, 0, stream>>>(Xb, W0T, a0src, a0dst, P, alsrc, aldst, N);
    k_agg<<<(N + 3) / 4, 256, 0, stream>>>(P, alsrc, aldst, offs, adj, b0, A, N, /*do_elu=*/1);

    // ---- layer 1 ----
    k_gemm_mfma<256><<<GB, 256, 0, stream>>>(A, W1T, a1src, a1dst, P, alsrc, aldst, N);
    k_agg<<<(N + 3) / 4, 256, 0, stream>>>(P, alsrc, aldst, offs, adj, b1, A, N, /*do_elu=*/0);

    // ---- pool + classify + softmax ----
    k_pool<<<256, 256, 0, stream>>>(A, pooled, N);
    k_final<<<1, 64, 0, stream>>>(pooled, clsW, clsb, out, N);
}

// Round 4
// 393.333 us; speedup vs baseline: 1.9312x; 1.1143x over previous
//
#include <hip/hip_runtime.h>
#include <hip/hip_bf16.h>

// GAT: 2-layer, N=50000, F=64, H=4, C=64, D=256, E=800000 (+N self loops)
// out = softmax(mean_pool(layer2) @ cls_W + cls_b) -> [1,16] f32
// Datapath: bf16 MFMA GEMMs (f32 accum, fused attention dots), fp8(e4m3) message
// gathers in aggregation, f32 attention logits/softmax.

#define NEG_SLOPE 0.2f
__device__ __forceinline__ float leaky(float e) { return fmaxf(e, NEG_SLOPE * e); }

typedef __bf16 bf16x8 __attribute__((ext_vector_type(8)));
typedef float  f32x4  __attribute__((ext_vector_type(4)));
typedef float  f32x2  __attribute__((ext_vector_type(2)));

#if __has_builtin(__builtin_amdgcn_cvt_pk_f32_fp8) && __has_builtin(__builtin_amdgcn_cvt_pk_fp8_f32)
#define USE_FP8 1
#else
#define USE_FP8 0
#endif

__device__ __forceinline__ float bfbits2f(unsigned int hi_bits) {
    union { unsigned int i; float f; } c; c.i = hi_bits; return c.f;
}
__device__ __forceinline__ unsigned short f2bf(float f) {
    union { float f; unsigned int i; } c; c.f = f;
    unsigned int x = c.i;
    x += 0x7fffu + ((x >> 16) & 1u);   // RNE
    return (unsigned short)(x >> 16);
}

// ---------------- CSR build ----------------

__global__ void k_init(int* deg, float* pooled, int N) {
    int i = blockIdx.x * blockDim.x + threadIdx.x;
    if (i < N) deg[i] = 1;  // self loop
    if (blockIdx.x == 0 && threadIdx.x < 256) pooled[threadIdx.x] = 0.f;
}

__global__ void k_hist(const int* __restrict__ ei, int* __restrict__ deg, int E) {
    int i = blockIdx.x * blockDim.x + threadIdx.x;
    if (i < E) atomicAdd(&deg[ei[E + i]], 1);
}

__global__ void k_scan1(const int* __restrict__ deg, int* __restrict__ offs, int* __restrict__ sums, int N) {
    __shared__ int tmp[256];
    int t = threadIdx.x;
    int i = blockIdx.x * 256 + t;
    int v = (i < N) ? deg[i] : 0;
    tmp[t] = v;
    __syncthreads();
    for (int off = 1; off < 256; off <<= 1) {
        int add = (t >= off) ? tmp[t - off] : 0;
        __syncthreads();
        tmp[t] += add;
        __syncthreads();
    }
    if (i < N) offs[i] = tmp[t] - v;
    if (t == 255) sums[blockIdx.x] = tmp[255];
}

__global__ void k_scan2(int* __restrict__ sums, int* __restrict__ offs, int nb, int N) {
    __shared__ int tmp[256];
    int t = threadIdx.x;
    int v = (t < nb) ? sums[t] : 0;
    tmp[t] = v;
    __syncthreads();
    for (int off = 1; off < 256; off <<= 1) {
        int add = (t >= off) ? tmp[t - off] : 0;
        __syncthreads();
        tmp[t] += add;
        __syncthreads();
    }
    if (t < nb) sums[t] = tmp[t] - v;
    if (t == 255) offs[N] = tmp[255];
}

__global__ void k_scan3(int* __restrict__ offs, int* __restrict__ cursor, const int* __restrict__ sums, int N) {
    int i = blockIdx.x * 256 + threadIdx.x;
    if (i < N) {
        int o = offs[i] + sums[blockIdx.x];
        offs[i] = o;
        cursor[i] = o;
    }
}

__global__ void k_fill(const int* __restrict__ ei, int* __restrict__ cursor, int* __restrict__ adj, int N, int E) {
    int i = blockIdx.x * blockDim.x + threadIdx.x;
    if (i >= E + N) return;
    int s, d;
    if (i < E) { s = ei[i]; d = ei[E + i]; }
    else       { s = i - E; d = i - E; }
    int pos = atomicAdd(&cursor[d], 1);
    adj[pos] = s;
}

// ---------------- converts ----------------

__global__ void k_cvt(const float* __restrict__ in, unsigned short* __restrict__ out, int n4) {
    int i = (blockIdx.x * blockDim.x + threadIdx.x);
    if (i < n4) {
        float4 v = *(const float4*)&in[i * 4];
        ushort4 o;
        o.x = f2bf(v.x); o.y = f2bf(v.y); o.z = f2bf(v.z); o.w = f2bf(v.w);
        *(ushort4*)&out[i * 4] = o;
    }
}

// W[K][256] f32 -> WT[256][K] bf16
template<int K>
__global__ void k_cvt_wT(const float* __restrict__ W, unsigned short* __restrict__ WT) {
    int t = blockIdx.x * 256 + threadIdx.x;   // t < K*256
    int k = t & (K - 1);
    int c = t / K;
    WT[(size_t)c * K + k] = f2bf(W[(size_t)k * 256 + c]);
}

// ---------------- MFMA GEMM + fused attention dots ----------------
// P[N][256](fp8) = X[N][K](bf16) @ W[K][256]; al{src,dst}[n][h] from f32 accum.
// block 256 = 4 waves; tile 64 rows x 256 cols; wave w handles cols w*64.. (== head w)
// no LDS: A-frags from global rows, B-frags from pre-transposed WT (L2-resident)

template<int K>
__global__ __launch_bounds__(256) void k_gemm_mfma(const unsigned short* __restrict__ Xb,
                                                   const unsigned short* __restrict__ WT,
                                                   const float* __restrict__ asrc,
                                                   const float* __restrict__ adst,
                                                   unsigned char* __restrict__ P,
                                                   float* __restrict__ alsrc,
                                                   float* __restrict__ aldst, int N) {
    const int t = threadIdx.x;
    const int w = t >> 6;          // wave index = head = col block
    const int l = t & 63;
    const int l16 = l & 15;
    const int lg = l >> 4;         // k-group 0..3
    const int row0 = blockIdx.x * 64;
    const int colbase = w * 64;

    f32x4 acc[4][4];
#pragma unroll
    for (int i = 0; i < 4; ++i)
#pragma unroll
        for (int j = 0; j < 4; ++j) acc[i][j] = (f32x4){0.f, 0.f, 0.f, 0.f};

#pragma unroll
    for (int k0 = 0; k0 < K; k0 += 32) {
        bf16x8 a[4], b[4];
#pragma unroll
        for (int fi = 0; fi < 4; ++fi) {
            int r = row0 + fi * 16 + l16;
            r = (r < N) ? r : (N - 1);
            a[fi] = *(const bf16x8*)&Xb[(size_t)r * K + k0 + lg * 8];
        }
#pragma unroll
        for (int fj = 0; fj < 4; ++fj) {
            int c = colbase + fj * 16 + l16;
            b[fj] = *(const bf16x8*)&WT[(size_t)c * K + k0 + lg * 8];
        }
#pragma unroll
        for (int fi = 0; fi < 4; ++fi)
#pragma unroll
            for (int fj = 0; fj < 4; ++fj)
                acc[fi][fj] = __builtin_amdgcn_mfma_f32_16x16x32_bf16(a[fi], b[fj], acc[fi][fj], 0, 0, 0);
    }

    // epilogue: store P (fp8 or bf16) + fused attention dots (f32)
    float aSv[4], aDv[4];
#pragma unroll
    for (int fj = 0; fj < 4; ++fj) {
        aSv[fj] = asrc[colbase + fj * 16 + l16];
        aDv[fj] = adst[colbase + fj * 16 + l16];
    }
#pragma unroll
    for (int fi = 0; fi < 4; ++fi) {
#pragma unroll
        for (int r = 0; r < 4; ++r) {
            int row = row0 + fi * 16 + lg * 4 + r;
            bool ok = (row < N);
            float ps = 0.f, pd = 0.f;
#pragma unroll
            for (int fj = 0; fj < 4; ++fj) {
                float v = acc[fi][fj][r];
                if (ok) {
#if USE_FP8
                    unsigned int q = __builtin_amdgcn_cvt_pk_fp8_f32(v, v, 0u, false);
                    P[(size_t)row * 256 + colbase + fj * 16 + l16] = (unsigned char)(q & 0xff);
#else
                    ((unsigned short*)P)[(size_t)row * 256 + colbase + fj * 16 + l16] = f2bf(v);
#endif
                }
                ps = fmaf(v, aSv[fj], ps);
                pd = fmaf(v, aDv[fj], pd);
            }
#pragma unroll
            for (int off = 1; off < 16; off <<= 1) {
                ps += __shfl_xor(ps, off, 64);
                pd += __shfl_xor(pd, off, 64);
            }
            if (ok && l16 == 0) {
                alsrc[(size_t)row * 4 + w] = ps;
                aldst[(size_t)row * 4 + w] = pd;
            }
        }
    }
}

// ---------------- aggregation: one WAVE per dst node, fp8 message gathers ----------------
// lane owns channels lane*4..lane*4+3 (head = lane>>4); per edge: one dword gather + dequant + 4 fmaf

__global__ __launch_bounds__(256) void k_agg(const unsigned char* __restrict__ P,
                                             const float* __restrict__ alsrc,
                                             const float* __restrict__ aldst,
                                             const int* __restrict__ offs,
                                             const int* __restrict__ adj,
                                             const float* __restrict__ bias,
                                             unsigned short* __restrict__ out, int N, int do_elu) {
    const int wv = threadIdx.x >> 6;
    const int lane = threadIdx.x & 63;
    const int d = blockIdx.x * 4 + wv;
    __shared__ float s_w[4][256];
    __shared__ int s_off[4][64];
    if (d >= N) return;

    const int s0 = offs[d];
    const int deg = offs[d + 1] - s0;
    const float4 ad = *(const float4*)&aldst[(size_t)d * 4];

    // first chunk of edges kept in registers
    int sfirst = 0;
    float4 e0 = make_float4(-1e30f, -1e30f, -1e30f, -1e30f);
    if (lane < deg) {
        sfirst = adj[s0 + lane];
        float4 as = *(const float4*)&alsrc[(size_t)sfirst * 4];
        e0.x = leaky(as.x + ad.x);
        e0.y = leaky(as.y + ad.y);
        e0.z = leaky(as.z + ad.z);
        e0.w = leaky(as.w + ad.w);
    }
    float4 mx = e0;
    for (int j = lane + 64; j < deg; j += 64) {
        int s = adj[s0 + j];
        float4 as = *(const float4*)&alsrc[(size_t)s * 4];
        mx.x = fmaxf(mx.x, leaky(as.x + ad.x));
        mx.y = fmaxf(mx.y, leaky(as.y + ad.y));
        mx.z = fmaxf(mx.z, leaky(as.z + ad.z));
        mx.w = fmaxf(mx.w, leaky(as.w + ad.w));
    }
#pragma unroll
    for (int off = 1; off < 64; off <<= 1) {
        mx.x = fmaxf(mx.x, __shfl_xor(mx.x, off, 64));
        mx.y = fmaxf(mx.y, __shfl_xor(mx.y, off, 64));
        mx.z = fmaxf(mx.z, __shfl_xor(mx.z, off, 64));
        mx.w = fmaxf(mx.w, __shfl_xor(mx.w, off, 64));
    }
    float4 sm = make_float4(0.f, 0.f, 0.f, 0.f);
    if (lane < deg) {
        sm.x = __expf(e0.x - mx.x);
        sm.y = __expf(e0.y - mx.y);
        sm.z = __expf(e0.z - mx.z);
        sm.w = __expf(e0.w - mx.w);
    }
    for (int j = lane + 64; j < deg; j += 64) {
        int s = adj[s0 + j];
        float4 as = *(const float4*)&alsrc[(size_t)s * 4];
        sm.x += __expf(leaky(as.x + ad.x) - mx.x);
        sm.y += __expf(leaky(as.y + ad.y) - mx.y);
        sm.z += __expf(leaky(as.z + ad.z) - mx.z);
        sm.w += __expf(leaky(as.w + ad.w) - mx.w);
    }
#pragma unroll
    for (int off = 1; off < 64; off <<= 1) {
        sm.x += __shfl_xor(sm.x, off, 64);
        sm.y += __shfl_xor(sm.y, off, 64);
        sm.z += __shfl_xor(sm.z, off, 64);
        sm.w += __shfl_xor(sm.w, off, 64);
    }
    float4 rd = make_float4(1.f / sm.x, 1.f / sm.y, 1.f / sm.z, 1.f / sm.w);

    // accumulate: per edge one dword (4 fp8) / dwordx2 (4 bf16) per lane
    const int head = lane >> 4;
    float4 acc = make_float4(0.f, 0.f, 0.f, 0.f);
#if USE_FP8
    const char* Pb = (const char*)P + (size_t)lane * 4;
    const int rowshift = 8;   // 256 B per fp8 row
#else
    const char* Pb = (const char*)P + (size_t)lane * 8;
    const int rowshift = 9;   // 512 B per bf16 row
#endif

    for (int base = 0; base < deg; base += 64) {
        int cl = min(64, deg - base);
        if (lane < cl) {
            float4 wgt;
            int s;
            if (base == 0) {
                s = sfirst;
                wgt.x = __expf(e0.x - mx.x) * rd.x;
                wgt.y = __expf(e0.y - mx.y) * rd.y;
                wgt.z = __expf(e0.z - mx.z) * rd.z;
                wgt.w = __expf(e0.w - mx.w) * rd.w;
            } else {
                s = adj[s0 + base + lane];
                float4 as = *(const float4*)&alsrc[(size_t)s * 4];
                wgt.x = __expf(leaky(as.x + ad.x) - mx.x) * rd.x;
                wgt.y = __expf(leaky(as.y + ad.y) - mx.y) * rd.y;
                wgt.z = __expf(leaky(as.z + ad.z) - mx.z) * rd.z;
                wgt.w = __expf(leaky(as.w + ad.w) - mx.w) * rd.w;
            }
            *(float4*)&s_w[wv][lane * 4] = wgt;
            s_off[wv][lane] = s << rowshift;  // byte offset of row
        }
        // per-wave LDS, wave-internal ordering: no block barrier needed
#pragma unroll 4
        for (int j = 0; j < cl; ++j) {
            float wgt = s_w[wv][j * 4 + head];
            int off = s_off[wv][j];
#if USE_FP8
            unsigned int pv = *(const unsigned int*)(Pb + off);
            f32x2 lo = __builtin_amdgcn_cvt_pk_f32_fp8(pv, false);
            f32x2 hi = __builtin_amdgcn_cvt_pk_f32_fp8(pv, true);
            acc.x = fmaf(wgt, lo[0], acc.x);
            acc.y = fmaf(wgt, lo[1], acc.y);
            acc.z = fmaf(wgt, hi[0], acc.z);
            acc.w = fmaf(wgt, hi[1], acc.w);
#else
            uint2 pv = *(const uint2*)(Pb + off);
            acc.x = fmaf(wgt, bfbits2f(pv.x << 16), acc.x);
            acc.y = fmaf(wgt, bfbits2f(pv.x & 0xffff0000u), acc.y);
            acc.z = fmaf(wgt, bfbits2f(pv.y << 16), acc.z);
            acc.w = fmaf(wgt, bfbits2f(pv.y & 0xffff0000u), acc.w);
#endif
        }
    }

    float4 b4 = *(const float4*)&bias[lane * 4];
    float4 v = make_float4(acc.x + b4.x, acc.y + b4.y, acc.z + b4.z, acc.w + b4.w);
    if (do_elu) {
        v.x = (v.x > 0.f) ? v.x : (__expf(v.x) - 1.f);
        v.y = (v.y > 0.f) ? v.y : (__expf(v.y) - 1.f);
        v.z = (v.z > 0.f) ? v.z : (__expf(v.z) - 1.f);
        v.w = (v.w > 0.f) ? v.w : (__expf(v.w) - 1.f);
    }
    ushort4 o;
    o.x = f2bf(v.x); o.y = f2bf(v.y); o.z = f2bf(v.z); o.w = f2bf(v.w);
    *(ushort4*)&out[(size_t)d * 256 + lane * 4] = o;
}

// ---------------- mean pool (column sums, bf16 input) ----------------

__global__ __launch_bounds__(256) void k_pool(const unsigned short* __restrict__ A, float* __restrict__ pooled, int N) {
    int t = threadIdx.x;
    float acc = 0.f;
    for (int r = blockIdx.x; r < N; r += gridDim.x)
        acc += bfbits2f(((unsigned int)A[(size_t)r * 256 + t]) << 16);
    atomicAdd(&pooled[t], acc);
}

// ---------------- classifier + softmax ----------------

__global__ void k_final(const float* __restrict__ pooled, const float* __restrict__ clsW,
                        const float* __restrict__ clsb, float* __restrict__ out, int N) {
    int t = threadIdx.x;  // 64 threads
    float logit = -1e30f;
    if (t < 16) {
        float acc = 0.f;
        for (int k = 0; k < 256; ++k)
            acc = fmaf(pooled[k], clsW[k * 16 + t], acc);
        logit = acc / (float)N + clsb[t];
    }
    float mx = logit;
#pragma unroll
    for (int off = 1; off < 16; off <<= 1) mx = fmaxf(mx, __shfl_xor(mx, off, 64));
    float ex = __expf(logit - mx);
    float sm = ex;
#pragma unroll
    for (int off = 1; off < 16; off <<= 1) sm += __shfl_xor(sm, off, 64);
    if (t < 16) out[t] = ex / sm;
}

// ---------------- launch ----------------

extern "C" void kernel_launch(void* const* d_in, const int* in_sizes, int n_in,
                              void* d_out, int out_size, void* d_ws, size_t ws_size,
                              hipStream_t stream) {
    const float* x     = (const float*)d_in[0];
    const int*   ei    = (const int*)d_in[1];
    const float* W0    = (const float*)d_in[2];
    const float* a0src = (const float*)d_in[3];
    const float* a0dst = (const float*)d_in[4];
    const float* b0    = (const float*)d_in[5];
    const float* W1    = (const float*)d_in[6];
    const float* a1src = (const float*)d_in[7];
    const float* a1dst = (const float*)d_in[8];
    const float* b1    = (const float*)d_in[9];
    const float* clsW  = (const float*)d_in[10];
    const float* clsb  = (const float*)d_in[11];
    float* out = (float*)d_out;

    const int N = in_sizes[0] / 64;   // 50000
    const int E = in_sizes[1] / 2;    // 800000

    char* w = (char*)d_ws;
    auto alloc = [&](size_t bytes) {
        char* p = w;
        w += (bytes + 255) & ~(size_t)255;
        return p;
    };
    unsigned short* Xb   = (unsigned short*)alloc((size_t)N * 64 * 2);
    unsigned short* W0T  = (unsigned short*)alloc((size_t)256 * 64 * 2);
    unsigned short* W1T  = (unsigned short*)alloc((size_t)256 * 256 * 2);
    unsigned char*  P    = (unsigned char*)alloc((size_t)N * 256 * 2);  // sized for bf16 fallback
    unsigned short* A    = (unsigned short*)alloc((size_t)N * 256 * 2);
    float* alsrc  = (float*)alloc((size_t)N * 4 * 4);
    float* aldst  = (float*)alloc((size_t)N * 4 * 4);
    int*   deg    = (int*)alloc((size_t)N * 4);
    int*   offs   = (int*)alloc((size_t)(N + 1) * 4);
    int*   cursor = (int*)alloc((size_t)N * 4);
    int*   sums   = (int*)alloc(1024 * 4);
    int*   adj    = (int*)alloc((size_t)(E + N) * 4);
    float* pooled = (float*)alloc(256 * 4);

    const int NB = (N + 255) / 256;  // 196 (<= 256 for k_scan2)

    // CSR build (by destination), includes self loops; also zeroes `pooled`
    k_init<<<NB, 256, 0, stream>>>(deg, pooled, N);
    k_hist<<<(E + 255) / 256, 256, 0, stream>>>(ei, deg, E);
    k_scan1<<<NB, 256, 0, stream>>>(deg, offs, sums, N);
    k_scan2<<<1, 256, 0, stream>>>(sums, offs, NB, N);
    k_scan3<<<NB, 256, 0, stream>>>(offs, cursor, sums, N);
    k_fill<<<(E + N + 255) / 256, 256, 0, stream>>>(ei, cursor, adj, N, E);

    // converts
    k_cvt<<<(N * 64 / 4 + 255) / 256, 256, 0, stream>>>(x, Xb, N * 64 / 4);
    k_cvt_wT<64><<<64, 256, 0, stream>>>(W0, W0T);
    k_cvt_wT<256><<<256, 256, 0, stream>>>(W1, W1T);

    const int GB = (N + 63) / 64;  // 782

    // ---- layer 0 ----
    k_gemm_mfma<64><<<GB, 256, 0, stream>>>(Xb, W0T, a0src, a0dst, P, alsrc, aldst, N);
    k_agg<<<(N + 3) / 4, 256, 0, stream>>>(P, alsrc, aldst, offs, adj, b0, A, N, /*do_elu=*/1);

    // ---- layer 1 ----
    k_gemm_mfma<256><<<GB, 256, 0, stream>>>(A, W1T, a1src, a1dst, P, alsrc, aldst, N);
    k_agg<<<(N + 3) / 4, 256, 0, stream>>>(P, alsrc, aldst, offs, adj, b1, A, N, /*do_elu=*/0);

    // ---- pool + classify + softmax ----
    k_pool<<<256, 256, 0, stream>>>(A, pooled, N);
    k_final<<<1, 64, 0, stream>>>(pooled, clsW, clsb, out, N);
}